// Round 5
// baseline (12.574 us; speedup 1.0000x reference)
//
#include <hip/hip_runtime.h>
#include <math.h>

// One block per 2 images (256 threads).
// Gate threads 0..3: SO(3) columns of layer-0 Rot(w); 4..7: M = Rot†ZRot for layer-1.
// Sim: pass0 threads 0..255 -> patches 0..255, pass1 threads 0..135 -> 256..391
//      (392 = 2 images x 196 patches); Bloch-vector closed form (validated R4).
// Head: 160 threads = 2 images x 10 classes x 8 lanes, 98 fma each, width-8 shuffle.
// Softmax: 20 threads, one per (image, class), fully parallel.
__global__ __launch_bounds__(256) void quanv_fused_kernel(
    const float* __restrict__ x,        // (B, 784)
    const float* __restrict__ params,   // (2,4,3) = 24 floats
    const float* __restrict__ head_w,   // (10, 784)
    const float* __restrict__ head_b,   // (10,)
    float* __restrict__ out,            // (B, 10)
    int B)
{
    __shared__ float col[4][8];      // per layer-0 wire: cxx,cxy,cxz,-, czx,czy,czz,-
    __shared__ float Mw[4][4];       // per layer-1 wire: m, wr, wi, -
    __shared__ float feats[2][784];
    __shared__ float logits_s[2][10];

    const int tid = threadIdx.x;
    const int b   = blockIdx.x;
    const int nimg = (2 * b + 2 <= B) ? 2 : (B - 2 * b);   // B is even in practice

    if (tid < 4) {
        const float phi   = params[tid * 3 + 0];
        const float theta = params[tid * 3 + 1];
        const float omega = params[tid * 3 + 2];
        const float cph = __cosf(phi),   sph = __sinf(phi);
        const float cth = __cosf(theta), sth = __sinf(theta);
        const float com = __cosf(omega), som = __sinf(omega);
        col[tid][0] = cth * cph * com - sph * som;   // col_x.x
        col[tid][1] = cth * cph * som + sph * com;   // col_x.y
        col[tid][2] = -sth * cph;                    // col_x.z
        col[tid][4] = sth * com;                     // col_z.x
        col[tid][5] = sth * som;                     // col_z.y
        col[tid][6] = cth;                           // col_z.z
    } else if (tid < 8) {
        const int w = tid - 4;
        const float phi   = params[12 + w * 3 + 0];
        const float theta = params[12 + w * 3 + 1];
        const float sth = __sinf(theta);
        Mw[w][0] = __cosf(theta);
        Mw[w][1] = -sth * __cosf(phi);
        Mw[w][2] = -sth * __sinf(phi);
    }
    __syncthreads();

#pragma unroll
    for (int pass = 0; pass < 2; ++pass) {
        const int p = tid + (pass << 8);
        if (p < nimg * 196) {
            const int im = (p >= 196) ? 1 : 0;
            const int lp = p - im * 196;
            const int pi_ = lp / 14, pj = lp % 14;
            const float* img = x + (size_t)(2 * b + im) * 784;
            const float2 row0 = *(const float2*)(img + (2 * pi_)     * 28 + 2 * pj);
            const float2 row1 = *(const float2*)(img + (2 * pi_ + 1) * 28 + 2 * pj);
            const float a[4] = { row0.x, row0.y, row1.x, row1.y };

            // Per-wire Bloch vector after RY(a) then layer-0 Rot
            float u0[4], u1[4], qre[4], qim[4], zb[4];
#pragma unroll
            for (int w = 0; w < 4; w++) {
                const float sa = __sinf(a[w]), ca = __cosf(a[w]);
                const float xx = fmaf(sa, col[w][0], ca * col[w][4]);
                const float yy = fmaf(sa, col[w][1], ca * col[w][5]);
                const float zz = fmaf(sa, col[w][2], ca * col[w][6]);
                zb[w]  = zz;
                u0[w]  = 0.5f + 0.5f * zz;
                u1[w]  = 0.5f - 0.5f * zz;
                qre[w] = 0.5f * xx;
                qim[w] = 0.5f * yy;
            }
            const float e0 = u0[0], e1 = u1[0], ze = zb[0], qr = qre[0], qi = qim[0];
            const float f0 = u0[1], f1 = u1[1], zf = zb[1], rr = qre[1], ri = qim[1];
            const float g0 = u0[2], g1 = u1[2], zg = zb[2], sr = qre[2], si = qim[2];
            const float zh = zb[3], tr = qre[3], ti = qim[3];

            const float m0 = Mw[0][0], w0r = Mw[0][1], w0i = Mw[0][2];
            const float m1 = Mw[1][0], w1r = Mw[1][1], w1i = Mw[1][2];
            const float m2 = Mw[2][0], w2r = Mw[2][1], w2i = Mw[2][2];
            const float m3 = Mw[3][0], w3r = Mw[3][1], w3i = Mw[3][2];

            // B-side aggregates (wires 2,3)
            const float pb   = 4.0f * tr * sr;
            const float PBi  = 2.0f * tr * si;
            const float w2s_m = w2r * sr - w2i * si;
            const float w2s_p = w2r * sr + w2i * si;
            const float Ga  = fmaf(m2, zg,  4.0f * tr * w2s_m);
            const float Gb  = fmaf(-m2, zg, 4.0f * tr * w2s_p);
            const float Gcr = w2r;
            const float Gci = fmaf(w2i, zg, 2.0f * m2 * PBi);

            // z3
            const float w3t_m = w3r * tr - w3i * ti;
            const float w3t_p = w3r * tr + w3i * ti;
            const float alpha = fmaf(m3, zh, 2.0f * w3t_m);
            const float beta  = fmaf(-m3, zh, 2.0f * w3t_p);
            const float dq    = g0 * alpha - g1 * beta;
            const float Kr = w3r;
            const float Ki = fmaf(2.0f * m3, ti, w3i * zh);
            const float Tr = sr * Kr - si * Ki;
            const float Ti = sr * Ki + si * Kr;
            const float ZA = ze * zf;
            const float z3 = fmaf(ZA, fmaf(m2, dq, -2.0f * w2i * Ti), 2.0f * w2r * Tr);

            // z0
            const float z0 = fmaf(m0, ze, 4.0f * rr * (w0r * qr - w0i * qi));

            // z1
            const float w1r_m = w1r * rr - w1i * ri;
            const float w1r_p = w1r * rr + w1i * ri;
            const float gam1  = fmaf(m1, zf, 2.0f * pb * w1r_m);
            const float del1  = fmaf(-m1, zf, 2.0f * pb * w1r_p);
            const float diag1 = e0 * gam1 - e1 * del1;
            const float L1r = pb * w1r;
            const float L1i = fmaf(2.0f * m1, ri, pb * w1i * zf);
            const float QL1r = qr * L1r - qi * L1i;
            const float QL1i = qr * L1i + qi * L1r;
            const float z1 = fmaf(m0, diag1, 2.0f * (w0r * QL1r - w0i * QL1i));

            // z2
            const float Wgr = w1r * Gcr - w1i * Gci;
            const float Wgi = w1r * Gci + w1i * Gcr;
            const float gam2 = fmaf(m1, Ga * f0 - Gb * f1, 2.0f * (Wgr * rr - Wgi * ri));
            const float del2 = fmaf(m1, Ga * f1 - Gb * f0, 2.0f * (Wgr * rr + Wgi * ri));
            const float diag2 = e0 * gam2 - e1 * del2;
            const float L2r = fmaf(m1 * (Ga - Gb), rr, Wgr);
            const float L2i = fmaf(m1 * (Ga + Gb), ri, Wgi * zf);
            const float QL2r = qr * L2r - qi * L2i;
            const float QL2i = qr * L2i + qi * L2r;
            const float z2 = fmaf(m0, diag2, 2.0f * (w0r * QL2r - w0i * QL2i));

            *(float4*)&feats[im][lp * 4] = make_float4(z0, z1, z2, z3);
        }
    }
    __syncthreads();

    // Head: 160 threads = im(2) x k(10) x g(8); acc over j = g + 8i, i<98
    if (tid < 160) {
        const int im = tid / 80;
        const int r  = tid - im * 80;
        const int k  = r >> 3, g = r & 7;
        if (im < nimg) {
            const float* hw = head_w + k * 784;
            const float* fv = feats[im];
            float acc0 = 0.0f, acc1 = 0.0f;
#pragma unroll
            for (int i = 0; i < 98; i += 2) {
                const int j0 = g + (i << 3);
                acc0 = fmaf(fv[j0],     hw[j0],     acc0);
                acc1 = fmaf(fv[j0 + 8], hw[j0 + 8], acc1);
            }
            float v = acc0 + acc1;
            v += __shfl_down(v, 4, 8);
            v += __shfl_down(v, 2, 8);
            v += __shfl_down(v, 1, 8);
            if (g == 0) logits_s[im][k] = v + head_b[k];
        }
    }
    __syncthreads();

    // Parallel log_softmax: one thread per (image, class)
    if (tid < 20) {
        const int im = tid / 10, k = tid - im * 10;
        if (im < nimg) {
            const float* l = logits_s[im];
            float mx = l[0];
#pragma unroll
            for (int j = 1; j < 10; j++) mx = fmaxf(mx, l[j]);
            float sum = 0.0f;
#pragma unroll
            for (int j = 0; j < 10; j++) sum += __expf(l[j] - mx);
            out[(size_t)(2 * b + im) * 10 + k] = l[k] - mx - __logf(sum);
        }
    }
}

extern "C" void kernel_launch(void* const* d_in, const int* in_sizes, int n_in,
                              void* d_out, int out_size, void* d_ws, size_t ws_size,
                              hipStream_t stream) {
    const float* x      = (const float*)d_in[0];
    const float* params = (const float*)d_in[1];
    const float* head_w = (const float*)d_in[2];
    const float* head_b = (const float*)d_in[3];
    float* out = (float*)d_out;

    const int B = in_sizes[0] / 784;
    const int nblocks = (B + 1) / 2;

    quanv_fused_kernel<<<nblocks, 256, 0, stream>>>(x, params, head_w, head_b, out, B);
}

// Round 6
// 11.949 us; speedup vs baseline: 1.0523x; 1.0523x over previous
//
#include <hip/hip_runtime.h>
#include <math.h>

// One block per image (256 threads).
// Gate threads 0..3: SO(3) columns of layer-0 Rot(w); 4..7: M = Rot†ZRot layer-1.
// Sim threads 0..195: per-patch Bloch-vector closed form (validated R4).
// Head: 256 threads, coalesced head_w loads, acc[10]; width-8 shuffle reduce
// (3 steps) -> red[32][10] in LDS -> 40-thread tree -> logits.
// Softmax: 10 threads in parallel (redundant max/LSE).
__global__ __launch_bounds__(256) void quanv_fused_kernel(
    const float* __restrict__ x,        // (B, 784)
    const float* __restrict__ params,   // (2,4,3) = 24 floats
    const float* __restrict__ head_w,   // (10, 784)
    const float* __restrict__ head_b,   // (10,)
    float* __restrict__ out,            // (B, 10)
    int B)
{
    __shared__ float col[4][8];      // per layer-0 wire: cxx,cxy,cxz,-, czx,czy,czz,-
    __shared__ float Mw[4][4];       // per layer-1 wire: m, wr, wi, -
    __shared__ float feats[784];
    __shared__ float red[32][10];    // 32 groups x 10 classes
    __shared__ float logits_s[10];

    const int tid = threadIdx.x;
    const int b   = blockIdx.x;

    if (tid < 4) {
        const float phi   = params[tid * 3 + 0];
        const float theta = params[tid * 3 + 1];
        const float omega = params[tid * 3 + 2];
        const float cph = __cosf(phi),   sph = __sinf(phi);
        const float cth = __cosf(theta), sth = __sinf(theta);
        const float com = __cosf(omega), som = __sinf(omega);
        col[tid][0] = cth * cph * com - sph * som;   // col_x.x
        col[tid][1] = cth * cph * som + sph * com;   // col_x.y
        col[tid][2] = -sth * cph;                    // col_x.z
        col[tid][4] = sth * com;                     // col_z.x
        col[tid][5] = sth * som;                     // col_z.y
        col[tid][6] = cth;                           // col_z.z
    } else if (tid < 8) {
        const int w = tid - 4;
        const float phi   = params[12 + w * 3 + 0];
        const float theta = params[12 + w * 3 + 1];
        const float sth = __sinf(theta);
        Mw[w][0] = __cosf(theta);
        Mw[w][1] = -sth * __cosf(phi);
        Mw[w][2] = -sth * __sinf(phi);
    }
    __syncthreads();

    if (tid < 196) {
        const int pi_ = tid / 14, pj = tid % 14;
        const float* img = x + (size_t)b * 784;
        const float2 row0 = *(const float2*)(img + (2 * pi_)     * 28 + 2 * pj);
        const float2 row1 = *(const float2*)(img + (2 * pi_ + 1) * 28 + 2 * pj);
        const float a[4] = { row0.x, row0.y, row1.x, row1.y };

        // Per-wire Bloch vector after RY(a) then layer-0 Rot
        float u0[4], u1[4], qre[4], qim[4], zb[4];
#pragma unroll
        for (int w = 0; w < 4; w++) {
            const float sa = __sinf(a[w]), ca = __cosf(a[w]);
            const float xx = fmaf(sa, col[w][0], ca * col[w][4]);
            const float yy = fmaf(sa, col[w][1], ca * col[w][5]);
            const float zz = fmaf(sa, col[w][2], ca * col[w][6]);
            zb[w]  = zz;
            u0[w]  = 0.5f + 0.5f * zz;
            u1[w]  = 0.5f - 0.5f * zz;
            qre[w] = 0.5f * xx;
            qim[w] = 0.5f * yy;
        }
        const float e0 = u0[0], e1 = u1[0], ze = zb[0], qr = qre[0], qi = qim[0];
        const float f0 = u0[1], f1 = u1[1], zf = zb[1], rr = qre[1], ri = qim[1];
        const float g0 = u0[2], g1 = u1[2], zg = zb[2], sr = qre[2], si = qim[2];
        const float zh = zb[3], tr = qre[3], ti = qim[3];

        const float m0 = Mw[0][0], w0r = Mw[0][1], w0i = Mw[0][2];
        const float m1 = Mw[1][0], w1r = Mw[1][1], w1i = Mw[1][2];
        const float m2 = Mw[2][0], w2r = Mw[2][1], w2i = Mw[2][2];
        const float m3 = Mw[3][0], w3r = Mw[3][1], w3i = Mw[3][2];

        // B-side aggregates (wires 2,3)
        const float pb   = 4.0f * tr * sr;
        const float PBi  = 2.0f * tr * si;
        const float w2s_m = w2r * sr - w2i * si;
        const float w2s_p = w2r * sr + w2i * si;
        const float Ga  = fmaf(m2, zg,  4.0f * tr * w2s_m);
        const float Gb  = fmaf(-m2, zg, 4.0f * tr * w2s_p);
        const float Gcr = w2r;
        const float Gci = fmaf(w2i, zg, 2.0f * m2 * PBi);

        // z3
        const float w3t_m = w3r * tr - w3i * ti;
        const float w3t_p = w3r * tr + w3i * ti;
        const float alpha = fmaf(m3, zh, 2.0f * w3t_m);
        const float beta  = fmaf(-m3, zh, 2.0f * w3t_p);
        const float dq    = g0 * alpha - g1 * beta;
        const float Kr = w3r;
        const float Ki = fmaf(2.0f * m3, ti, w3i * zh);
        const float Tr = sr * Kr - si * Ki;
        const float Ti = sr * Ki + si * Kr;
        const float ZA = ze * zf;
        const float z3 = fmaf(ZA, fmaf(m2, dq, -2.0f * w2i * Ti), 2.0f * w2r * Tr);

        // z0
        const float z0 = fmaf(m0, ze, 4.0f * rr * (w0r * qr - w0i * qi));

        // z1
        const float w1r_m = w1r * rr - w1i * ri;
        const float w1r_p = w1r * rr + w1i * ri;
        const float gam1  = fmaf(m1, zf, 2.0f * pb * w1r_m);
        const float del1  = fmaf(-m1, zf, 2.0f * pb * w1r_p);
        const float diag1 = e0 * gam1 - e1 * del1;
        const float L1r = pb * w1r;
        const float L1i = fmaf(2.0f * m1, ri, pb * w1i * zf);
        const float QL1r = qr * L1r - qi * L1i;
        const float QL1i = qr * L1i + qi * L1r;
        const float z1 = fmaf(m0, diag1, 2.0f * (w0r * QL1r - w0i * QL1i));

        // z2
        const float Wgr = w1r * Gcr - w1i * Gci;
        const float Wgi = w1r * Gci + w1i * Gcr;
        const float gam2 = fmaf(m1, Ga * f0 - Gb * f1, 2.0f * (Wgr * rr - Wgi * ri));
        const float del2 = fmaf(m1, Ga * f1 - Gb * f0, 2.0f * (Wgr * rr + Wgi * ri));
        const float diag2 = e0 * gam2 - e1 * del2;
        const float L2r = fmaf(m1 * (Ga - Gb), rr, Wgr);
        const float L2i = fmaf(m1 * (Ga + Gb), ri, Wgi * zf);
        const float QL2r = qr * L2r - qi * L2i;
        const float QL2i = qr * L2i + qi * L2r;
        const float z2 = fmaf(m0, diag2, 2.0f * (w0r * QL2r - w0i * QL2i));

        *(float4*)&feats[tid * 4] = make_float4(z0, z1, z2, z3);
    }
    __syncthreads();

    // Head accumulate: coalesced head_w loads (tid + 256i)
    float acc[10];
#pragma unroll
    for (int k = 0; k < 10; k++) acc[k] = 0.0f;
#pragma unroll
    for (int i = 0; i < 3; i++) {
        const int j = tid + i * 256;
        const float f = feats[j];
#pragma unroll
        for (int k = 0; k < 10; k++) acc[k] = fmaf(f, head_w[k * 784 + j], acc[k]);
    }
    if (tid < 16) {
        const int j = tid + 768;
        const float f = feats[j];
#pragma unroll
        for (int k = 0; k < 10; k++) acc[k] = fmaf(f, head_w[k * 784 + j], acc[k]);
    }

    // Width-8 shuffle reduce (3 steps), group leaders write red[group][k]
    {
        const int grp = tid >> 3;
#pragma unroll
        for (int k = 0; k < 10; k++) {
            float v = acc[k];
            v += __shfl_down(v, 4, 8);
            v += __shfl_down(v, 2, 8);
            v += __shfl_down(v, 1, 8);
            if ((tid & 7) == 0) red[grp][k] = v;
        }
    }
    __syncthreads();

    // 40-thread finish: (k,g) g<4, each sums 8 groups, width-4 shuffle
    if (tid < 40) {
        const int k = tid >> 2, g = tid & 3;
        float v = 0.0f;
#pragma unroll
        for (int t = 0; t < 8; t++) v += red[g * 8 + t][k];
        v += __shfl_down(v, 2, 4);
        v += __shfl_down(v, 1, 4);
        if (g == 0) logits_s[k] = v + head_b[k];
    }
    __syncthreads();

    // Parallel log_softmax: one thread per class
    if (tid < 10) {
        float mx = logits_s[0];
#pragma unroll
        for (int j = 1; j < 10; j++) mx = fmaxf(mx, logits_s[j]);
        float sum = 0.0f;
#pragma unroll
        for (int j = 0; j < 10; j++) sum += __expf(logits_s[j] - mx);
        out[(size_t)b * 10 + tid] = logits_s[tid] - mx - __logf(sum);
    }
}

extern "C" void kernel_launch(void* const* d_in, const int* in_sizes, int n_in,
                              void* d_out, int out_size, void* d_ws, size_t ws_size,
                              hipStream_t stream) {
    const float* x      = (const float*)d_in[0];
    const float* params = (const float*)d_in[1];
    const float* head_w = (const float*)d_in[2];
    const float* head_b = (const float*)d_in[3];
    float* out = (float*)d_out;

    const int B = in_sizes[0] / 784;

    quanv_fused_kernel<<<B, 256, 0, stream>>>(x, params, head_w, head_b, out, B);
}

// Round 7
// 11.349 us; speedup vs baseline: 1.1079x; 1.0529x over previous
//
#include <hip/hip_runtime.h>
#include <math.h>

// One block per image.
// Gate threads 0..3: SO(3) columns (col_x, col_z) of layer-0 Rot(w) Bloch rotation.
// Gate threads 4..7: M = Rot†·Z·Rot for layer-1 wire w: m=cosθ, w=-sinθ e^{iφ}.
// Sim threads 0..195: per-patch — per-wire Bloch vectors, then z0..z3 as closed-form
// bilinear aggregates (all layer-1 gates + trailing CNOTs pushed into observables).
// Then 784x10 head + log_softmax in-block.
// NOTE (R5/R6 post-mortems): keep this exact scaffolding — 2-img/block with
// strided head loads (+1.25us) and width-8 reduce + LDS tree (+0.63us) both
// regressed vs this structure. Body is ~2us over a ~9.4us launch/graph floor.
__global__ __launch_bounds__(256) void quanv_fused_kernel(
    const float* __restrict__ x,        // (B, 784)
    const float* __restrict__ params,   // (2,4,3) = 24 floats
    const float* __restrict__ head_w,   // (10, 784)
    const float* __restrict__ head_b,   // (10,)
    float* __restrict__ out,            // (B, 10)
    int B)
{
    __shared__ float col[4][8];   // per layer-0 wire: cxx,cxy,cxz,-, czx,czy,czz,-
    __shared__ float Mw[4][4];    // per layer-1 wire: m, wr, wi, -
    __shared__ float feats[784];
    __shared__ float red[10][4];
    __shared__ float logits_s[10];

    const int tid = threadIdx.x;
    const int b   = blockIdx.x;

    if (tid < 4) {
        // layer-0 Rot(phi,theta,omega) = RZ(omega) RY(theta) RZ(phi) as SO(3);
        // need columns R*x_hat and R*z_hat (input Bloch = (sin a, 0, cos a)).
        const float phi   = params[tid * 3 + 0];
        const float theta = params[tid * 3 + 1];
        const float omega = params[tid * 3 + 2];
        const float cph = __cosf(phi),   sph = __sinf(phi);
        const float cth = __cosf(theta), sth = __sinf(theta);
        const float com = __cosf(omega), som = __sinf(omega);
        col[tid][0] = cth * cph * com - sph * som;   // col_x.x
        col[tid][1] = cth * cph * som + sph * com;   // col_x.y
        col[tid][2] = -sth * cph;                    // col_x.z
        col[tid][4] = sth * com;                     // col_z.x
        col[tid][5] = sth * som;                     // col_z.y
        col[tid][6] = cth;                           // col_z.z
    } else if (tid < 8) {
        const int w = tid - 4;
        const float phi   = params[12 + w * 3 + 0];
        const float theta = params[12 + w * 3 + 1];
        const float sth = __sinf(theta);
        Mw[w][0] = __cosf(theta);
        Mw[w][1] = -sth * __cosf(phi);
        Mw[w][2] = -sth * __sinf(phi);
    }
    __syncthreads();

    if (tid < 196) {
        const int pi_ = tid / 14, pj = tid % 14;
        const float* img = x + (size_t)b * 784;
        const float2 row0 = *(const float2*)(img + (2 * pi_)     * 28 + 2 * pj);
        const float2 row1 = *(const float2*)(img + (2 * pi_ + 1) * 28 + 2 * pj);
        const float a[4] = { row0.x, row0.y, row1.x, row1.y };

        // Per-wire Bloch vector after RY(a) then layer-0 Rot:
        // (x,y,z) = sin(a)*col_x + cos(a)*col_z
        // primitives: u0=(1+z)/2, u1=(1-z)/2 (pop.), q=(x+iy)/2 (coherence)
        float u0[4], u1[4], qre[4], qim[4], zb[4];
#pragma unroll
        for (int w = 0; w < 4; w++) {
            const float sa = __sinf(a[w]), ca = __cosf(a[w]);
            const float xx = fmaf(sa, col[w][0], ca * col[w][4]);
            const float yy = fmaf(sa, col[w][1], ca * col[w][5]);
            const float zz = fmaf(sa, col[w][2], ca * col[w][6]);
            zb[w]  = zz;
            u0[w]  = 0.5f + 0.5f * zz;
            u1[w]  = 0.5f - 0.5f * zz;
            qre[w] = 0.5f * xx;
            qim[w] = 0.5f * yy;
        }
        // naming: wire0 (e,q), wire1 (f,r), wire2 (g,s), wire3 (h,t)
        const float e0 = u0[0], e1 = u1[0], ze = zb[0], qr = qre[0], qi = qim[0];
        const float f0 = u0[1], f1 = u1[1], zf = zb[1], rr = qre[1], ri = qim[1];
        const float g0 = u0[2], g1 = u1[2], zg = zb[2], sr = qre[2], si = qim[2];
        const float zh = zb[3], tr = qre[3], ti = qim[3];

        const float m0 = Mw[0][0], w0r = Mw[0][1], w0i = Mw[0][2];
        const float m1 = Mw[1][0], w1r = Mw[1][1], w1i = Mw[1][2];
        const float m2 = Mw[2][0], w2r = Mw[2][1], w2i = Mw[2][2];
        const float m3 = Mw[3][0], w3r = Mw[3][1], w3i = Mw[3][2];

        // ---- B-side aggregates (wires 2,3) ----
        const float pb   = 4.0f * tr * sr;
        const float PBi  = 2.0f * tr * si;
        const float w2s_m = w2r * sr - w2i * si;
        const float w2s_p = w2r * sr + w2i * si;
        const float Ga  = fmaf(m2, zg,  4.0f * tr * w2s_m);   // G2(0,0)
        const float Gb  = fmaf(-m2, zg, 4.0f * tr * w2s_p);   // G2(1,1)
        const float Gcr = w2r;                                 // G2(0,1) real
        const float Gci = fmaf(w2i, zg, 2.0f * m2 * PBi);      // G2(0,1) imag

        // ---- z3 ----
        const float w3t_m = w3r * tr - w3i * ti;
        const float w3t_p = w3r * tr + w3i * ti;
        const float alpha = fmaf(m3, zh, 2.0f * w3t_m);
        const float beta  = fmaf(-m3, zh, 2.0f * w3t_p);
        const float dq    = g0 * alpha - g1 * beta;
        const float Kr = w3r;
        const float Ki = fmaf(2.0f * m3, ti, w3i * zh);
        const float Tr = sr * Kr - si * Ki;
        const float Ti = sr * Ki + si * Kr;
        const float ZA = ze * zf;
        const float z3 = fmaf(ZA, fmaf(m2, dq, -2.0f * w2i * Ti), 2.0f * w2r * Tr);

        // ---- z0 ----
        const float z0 = fmaf(m0, ze, 4.0f * rr * (w0r * qr - w0i * qi));

        // ---- z1 ----
        const float w1r_m = w1r * rr - w1i * ri;
        const float w1r_p = w1r * rr + w1i * ri;
        const float gam1  = fmaf(m1, zf, 2.0f * pb * w1r_m);
        const float del1  = fmaf(-m1, zf, 2.0f * pb * w1r_p);
        const float diag1 = e0 * gam1 - e1 * del1;
        const float L1r = pb * w1r;
        const float L1i = fmaf(2.0f * m1, ri, pb * w1i * zf);
        const float QL1r = qr * L1r - qi * L1i;
        const float QL1i = qr * L1i + qi * L1r;
        const float z1 = fmaf(m0, diag1, 2.0f * (w0r * QL1r - w0i * QL1i));

        // ---- z2 ----
        const float Wgr = w1r * Gcr - w1i * Gci;
        const float Wgi = w1r * Gci + w1i * Gcr;
        const float gam2 = fmaf(m1, Ga * f0 - Gb * f1, 2.0f * (Wgr * rr - Wgi * ri));
        const float del2 = fmaf(m1, Ga * f1 - Gb * f0, 2.0f * (Wgr * rr + Wgi * ri));
        const float diag2 = e0 * gam2 - e1 * del2;
        const float L2r = fmaf(m1 * (Ga - Gb), rr, Wgr);
        const float L2i = fmaf(m1 * (Ga + Gb), ri, Wgi * zf);
        const float QL2r = qr * L2r - qi * L2i;
        const float QL2i = qr * L2i + qi * L2r;
        const float z2 = fmaf(m0, diag2, 2.0f * (w0r * QL2r - w0i * QL2i));

        feats[tid * 4 + 0] = z0;
        feats[tid * 4 + 1] = z1;
        feats[tid * 4 + 2] = z2;
        feats[tid * 4 + 3] = z3;
    }
    __syncthreads();

    // Head: logits[k] = sum_j feats[j] * head_w[k*784+j] + head_b[k]
    float acc[10];
#pragma unroll
    for (int k = 0; k < 10; k++) acc[k] = 0.0f;
#pragma unroll
    for (int i = 0; i < 3; i++) {
        const int j = tid + i * 256;
        const float f = feats[j];
#pragma unroll
        for (int k = 0; k < 10; k++) acc[k] = fmaf(f, head_w[k * 784 + j], acc[k]);
    }
    if (tid < 16) {
        const int j = tid + 768;
        const float f = feats[j];
#pragma unroll
        for (int k = 0; k < 10; k++) acc[k] = fmaf(f, head_w[k * 784 + j], acc[k]);
    }
    const int lane = tid & 63, wid = tid >> 6;
#pragma unroll
    for (int k = 0; k < 10; k++) {
        float v = acc[k];
#pragma unroll
        for (int off = 32; off > 0; off >>= 1) v += __shfl_down(v, off, 64);
        if (lane == 0) red[k][wid] = v;
    }
    __syncthreads();
    if (tid < 10) {
        logits_s[tid] = red[tid][0] + red[tid][1] + red[tid][2] + red[tid][3]
                        + head_b[tid];
    }
    __syncthreads();
    if (tid == 0) {
        float mx = logits_s[0];
#pragma unroll
        for (int k = 1; k < 10; k++) mx = fmaxf(mx, logits_s[k]);
        float sum = 0.0f;
#pragma unroll
        for (int k = 0; k < 10; k++) sum += __expf(logits_s[k] - mx);
        const float lse = __logf(sum);
        float* o = out + (size_t)b * 10;
#pragma unroll
        for (int k = 0; k < 10; k++) o[k] = logits_s[k] - mx - lse;
    }
}

extern "C" void kernel_launch(void* const* d_in, const int* in_sizes, int n_in,
                              void* d_out, int out_size, void* d_ws, size_t ws_size,
                              hipStream_t stream) {
    const float* x      = (const float*)d_in[0];
    const float* params = (const float*)d_in[1];
    const float* head_w = (const float*)d_in[2];
    const float* head_b = (const float*)d_in[3];
    float* out = (float*)d_out;

    const int B = in_sizes[0] / 784;

    quanv_fused_kernel<<<B, 256, 0, stream>>>(x, params, head_w, head_b, out, B);
}